// Round 1
// baseline (267.215 us; speedup 1.0000x reference)
//
#include <hip/hip_runtime.h>
#include <math.h>

#define T_STEPS 9
#define D_IN    512
#define HID     64
#define G4      256   // 4*HID

// ---------------------------------------------------------------------------
// sigmoid / tanh via hardware exp. fsig is overflow-safe by construction;
// ftanh uses exp(-2|x|) to avoid inf/inf.
__device__ __forceinline__ float fsig(float x) {
    return 1.0f / (1.0f + __expf(-x));
}
__device__ __forceinline__ float ftanh(float x) {
    float t = __expf(-2.0f * fabsf(x));
    float r = (1.0f - t) / (1.0f + t);
    return copysignf(r, x);
}

// ---------------------------------------------------------------------------
// Kernel 1: xg[M, 256] = x[M, 512] @ Wx[512, 256]    (bias folded into rec)
// BM=64, BN=64, BK=32, 256 threads, 4x4 outputs per thread.
__global__ __launch_bounds__(256)
void xg_gemm(const float* __restrict__ x, const float* __restrict__ w,
             float* __restrict__ xg, int M)
{
    __shared__ float As[32][64 + 4];   // [k][m], row = 68 floats (16B-aligned rows)
    __shared__ float Bs[32][64 + 4];   // [k][n]

    const int t  = threadIdx.x;
    const int m0 = blockIdx.x * 64;
    const int n0 = blockIdx.y * 64;
    const int tx = t & 15;             // n micro-tile
    const int ty = t >> 4;             // m micro-tile

    // A loader: thread covers rows (t>>3) and (t>>3)+32, k-quad (t&7)*4
    const int ar = t >> 3;
    const int ak = (t & 7) * 4;
    // B loader: rows (t>>4) and (t>>4)+16 of w-tile, n-quad (t&15)*4
    const int br = t >> 4;
    const int bn = (t & 15) * 4;

    float acc[4][4] = {};

    for (int k0 = 0; k0 < D_IN; k0 += 32) {
        __syncthreads();
        // load A tile, transposed into As[k][m]
        {
            float4 v0 = *(const float4*)&x[(size_t)(m0 + ar)      * D_IN + k0 + ak];
            float4 v1 = *(const float4*)&x[(size_t)(m0 + ar + 32) * D_IN + k0 + ak];
            As[ak + 0][ar]      = v0.x; As[ak + 1][ar]      = v0.y;
            As[ak + 2][ar]      = v0.z; As[ak + 3][ar]      = v0.w;
            As[ak + 0][ar + 32] = v1.x; As[ak + 1][ar + 32] = v1.y;
            As[ak + 2][ar + 32] = v1.z; As[ak + 3][ar + 32] = v1.w;
        }
        // load B tile (already [k][n] in global)
        {
            *(float4*)&Bs[br][bn]      = *(const float4*)&w[(size_t)(k0 + br)      * G4 + n0 + bn];
            *(float4*)&Bs[br + 16][bn] = *(const float4*)&w[(size_t)(k0 + br + 16) * G4 + n0 + bn];
        }
        __syncthreads();

        #pragma unroll
        for (int kk = 0; kk < 32; ++kk) {
            float4 a = *(const float4*)&As[kk][ty * 4];
            float4 b = *(const float4*)&Bs[kk][tx * 4];
            float av[4] = {a.x, a.y, a.z, a.w};
            float bv[4] = {b.x, b.y, b.z, b.w};
            #pragma unroll
            for (int i = 0; i < 4; ++i)
                #pragma unroll
                for (int j = 0; j < 4; ++j)
                    acc[i][j] = fmaf(av[i], bv[j], acc[i][j]);
        }
    }

    #pragma unroll
    for (int i = 0; i < 4; ++i) {
        float4 v = {acc[i][0], acc[i][1], acc[i][2], acc[i][3]};
        *(float4*)&xg[(size_t)(m0 + ty * 4 + i) * G4 + n0 + tx * 4] = v;
    }
}

// ---------------------------------------------------------------------------
// Kernel 2: the recurrence. One wave handles 4 batch elements; lane u owns
// hidden unit u. Wh staged in LDS interleaved as sW[k*256 + u*4 + g] so each
// lane fetches its 4 gate weights for a given k with one ds_read_b128.
// h broadcast across lanes via __shfl (k is uniform -> readlane).
__global__ __launch_bounds__(256)
void lstm_rec(const float* __restrict__ xg, const float* __restrict__ kern,
              const float* __restrict__ bias, float* __restrict__ out, int B)
{
    __shared__ float sW[HID * G4];     // 64 KB exactly

    const int t    = threadIdx.x;
    const int wave = t >> 6;
    const int u    = t & 63;

    // stage Wh = kern[512.., :] into interleaved LDS layout
    const float* Wh = kern + (size_t)D_IN * G4;
    for (int i = t; i < HID * G4; i += 256) {
        int k   = i >> 8;          // 0..63
        int rem = i & 255;
        int g   = rem >> 6;        // gate 0..3 (i,j,f,o)
        int uu  = rem & 63;        // hidden unit
        sW[k * G4 + uu * 4 + g] = Wh[i];
    }
    __syncthreads();

    const int b0 = blockIdx.x * 16 + wave * 4;   // first of 4 batch elements

    const float b_i = bias[u];
    const float b_j = bias[64 + u];
    const float b_f = bias[128 + u] + 1.0f;      // FORGET_BIAS folded in
    const float b_o = bias[192 + u];

    float h[4] = {0.f, 0.f, 0.f, 0.f};
    float c[4] = {0.f, 0.f, 0.f, 0.f};

    const float* xgb = xg + (size_t)b0 * (T_STEPS * G4);

    for (int step = 0; step < T_STEPS; ++step) {
        float gi[4], gj[4], gf[4], go[4];
        #pragma unroll
        for (int bb = 0; bb < 4; ++bb) {
            const float* p = xgb + bb * (T_STEPS * G4) + step * G4;
            gi[bb] = p[u]       + b_i;
            gj[bb] = p[64 + u]  + b_j;
            gf[bb] = p[128 + u] + b_f;
            go[bb] = p[192 + u] + b_o;
        }

        #pragma unroll 16
        for (int k = 0; k < HID; ++k) {
            float4 w = *(const float4*)&sW[k * G4 + u * 4];
            #pragma unroll
            for (int bb = 0; bb < 4; ++bb) {
                float hk = __shfl(h[bb], k);
                gi[bb] = fmaf(hk, w.x, gi[bb]);
                gj[bb] = fmaf(hk, w.y, gj[bb]);
                gf[bb] = fmaf(hk, w.z, gf[bb]);
                go[bb] = fmaf(hk, w.w, go[bb]);
            }
        }

        #pragma unroll
        for (int bb = 0; bb < 4; ++bb) {
            float ii = fsig(gi[bb]);
            float ff = fsig(gf[bb]);           // forget bias already in gf
            float oo = fsig(go[bb]);
            float jj = ftanh(gj[bb]);
            c[bb] = ff * c[bb] + ii * jj;
            float hn = oo * ftanh(c[bb]);
            h[bb] = hn;
            out[((size_t)(b0 + bb) * T_STEPS + step) * HID + u] = hn;
        }
    }
}

// ---------------------------------------------------------------------------
extern "C" void kernel_launch(void* const* d_in, const int* in_sizes, int n_in,
                              void* d_out, int out_size, void* d_ws, size_t ws_size,
                              hipStream_t stream)
{
    const float* x    = (const float*)d_in[0];
    const float* kern = (const float*)d_in[1];
    const float* bias = (const float*)d_in[2];
    float* out = (float*)d_out;
    float* xg  = (float*)d_ws;   // M x 256 fp32 = 37.75 MB

    const int B = in_sizes[0] / (T_STEPS * D_IN);   // 4096
    const int M = B * T_STEPS;                      // 36864

    dim3 g1(M / 64, G4 / 64);
    xg_gemm<<<g1, 256, 0, stream>>>(x, kern, xg, M);

    lstm_rec<<<B / 16, 256, 0, stream>>>(xg, kern, bias, out, B);
}

// Round 3
// 158.793 us; speedup vs baseline: 1.6828x; 1.6828x over previous
//
#include <hip/hip_runtime.h>
#include <math.h>

#define T_STEPS 9
#define D_IN    512
#define HID     64
#define G4      256   // 4*HID

typedef short  short8 __attribute__((ext_vector_type(8)));
typedef float  f32x4  __attribute__((ext_vector_type(4)));
typedef unsigned int uint;
typedef unsigned short ushort;

// ---------------------------------------------------------------------------
// helpers
__device__ __forceinline__ ushort f2bf(float f) {
    uint u = __float_as_uint(f);
    u = (u + 0x7FFFu + ((u >> 16) & 1u)) >> 16;   // RNE
    return (ushort)u;
}
__device__ __forceinline__ float bf2f(ushort b) {
    return __uint_as_float(((uint)b) << 16);
}
__device__ __forceinline__ float fsig(float x) {
    return 1.0f / (1.0f + __expf(-x));
}
__device__ __forceinline__ float ftanh(float x) {
    float t = __expf(-2.0f * fabsf(x));
    float r = (1.0f - t) / (1.0f + t);
    return copysignf(r, x);
}
// async global->LDS, 16 B per lane; lds base must be wave-uniform
__device__ __forceinline__ void gl_lds16(const void* g, void* l) {
    __builtin_amdgcn_global_load_lds(
        (const __attribute__((address_space(1))) unsigned int*)g,
        (__attribute__((address_space(3))) unsigned int*)l, 16, 0, 0);
}

// ---------------------------------------------------------------------------
// Prepass: convert weights to bf16 in MFMA-staging layouts.
// WxT: [nblk(2)][k0(16)][qk(4)][n(128)][j(8)]  (131072 elems, 256 KB)
// WhT: [kq(8)][n(256)][j(8)]                   (16384 elems, 32 KB)
__global__ __launch_bounds__(256)
void prep_w(const float* __restrict__ kern, ushort* __restrict__ wxT,
            ushort* __restrict__ whT)
{
    int i = blockIdx.x * 256 + threadIdx.x;
    if (i < 131072) {
        int j   = i & 7;
        int n   = (i >> 3) & 127;
        int qk  = (i >> 10) & 3;
        int k0i = (i >> 12) & 15;
        int nb  = i >> 16;
        int k = k0i * 32 + qk * 8 + j;
        int g = nb * 128 + n;
        wxT[i] = f2bf(kern[(size_t)k * G4 + g]);
    } else {
        int i2 = i - 131072;
        int j  = i2 & 7;
        int n  = (i2 >> 3) & 255;
        int kq = i2 >> 11;
        int k  = kq * 8 + j;
        whT[i2] = f2bf(kern[(size_t)(D_IN + k) * G4 + n]);
    }
}

// ---------------------------------------------------------------------------
// Kernel 1: xg[M,256] = bf16mfma( x[M,512] @ Wx[512,256] ), stored bf16.
// 128x128 tile, BK=32, 256 threads (4 waves in 2x2, each 64x64 = 4x4 MFMA tiles).
// LDS chunk layout [qk][row][8j] -> conflict-free ds_read_b128 fragments.
__global__ __launch_bounds__(256)
void xg_gemm(const float* __restrict__ x, const ushort* __restrict__ wxT,
             ushort* __restrict__ xg, int M)
{
    __shared__ ushort sA[4 * 128 * 8];   // 8 KB
    __shared__ ushort sB[4 * 128 * 8];   // 8 KB

    const int t = threadIdx.x;
    const int w = t >> 6, l = t & 63;
    const int lane15 = l & 15, quad = l >> 4;
    const int m0 = blockIdx.x * 128;
    const int nb = blockIdx.y;           // 0..1
    const int wm = w >> 1, wn = w & 1;

    // A-stage mapping: thread covers row ar, k-half ah*16..+15
    const int ar = t >> 1, ah = t & 1;
    const float* asrc = x + (size_t)(m0 + ar) * D_IN + ah * 16;
    const ushort* btile = wxT + (size_t)nb * 65536;   // elems

    f32x4 acc[4][4];
    #pragma unroll
    for (int i = 0; i < 4; ++i)
        #pragma unroll
        for (int j = 0; j < 4; ++j)
            acc[i][j] = (f32x4){0.f, 0.f, 0.f, 0.f};

    for (int k0 = 0; k0 < 16; ++k0) {
        __syncthreads();
        // ---- stage A: 16 fp32 -> 16 bf16, two 16B LDS writes
        {
            const float4* s = (const float4*)(asrc + k0 * 32);
            float4 v0 = s[0], v1 = s[1], v2 = s[2], v3 = s[3];
            uint4 lo, hi;
            lo.x = f2bf(v0.x) | ((uint)f2bf(v0.y) << 16);
            lo.y = f2bf(v0.z) | ((uint)f2bf(v0.w) << 16);
            lo.z = f2bf(v1.x) | ((uint)f2bf(v1.y) << 16);
            lo.w = f2bf(v1.z) | ((uint)f2bf(v1.w) << 16);
            hi.x = f2bf(v2.x) | ((uint)f2bf(v2.y) << 16);
            hi.y = f2bf(v2.z) | ((uint)f2bf(v2.w) << 16);
            hi.z = f2bf(v3.x) | ((uint)f2bf(v3.y) << 16);
            hi.w = f2bf(v3.z) | ((uint)f2bf(v3.w) << 16);
            *(uint4*)&sA[((ah * 2 + 0) * 128 + ar) * 8] = lo;
            *(uint4*)&sA[((ah * 2 + 1) * 128 + ar) * 8] = hi;
        }
        // ---- stage B: 8 KB via DMA (2 x 1KB per wave)
        {
            const char* gb = (const char*)(btile + (size_t)k0 * 4096);
            char* lb = (char*)sB;
            #pragma unroll
            for (int q = 0; q < 2; ++q) {
                int off = w * 2048 + q * 1024;
                gl_lds16(gb + off + l * 16, lb + off);
            }
        }
        __syncthreads();

        short8 aF[4], bF[4];
        #pragma unroll
        for (int s = 0; s < 4; ++s)
            aF[s] = *(const short8*)&sA[(quad * 128 + wm * 64 + s * 16 + lane15) * 8];
        #pragma unroll
        for (int s = 0; s < 4; ++s)
            bF[s] = *(const short8*)&sB[(quad * 128 + wn * 64 + s * 16 + lane15) * 8];
        #pragma unroll
        for (int i = 0; i < 4; ++i)
            #pragma unroll
            for (int j = 0; j < 4; ++j)
                acc[i][j] = __builtin_amdgcn_mfma_f32_16x16x32_bf16(aF[i], bF[j], acc[i][j], 0, 0, 0);
    }

    // epilogue: C/D layout col=lane&15, row=quad*4+reg
    #pragma unroll
    for (int i = 0; i < 4; ++i)
        #pragma unroll
        for (int j = 0; j < 4; ++j)
            #pragma unroll
            for (int r = 0; r < 4; ++r) {
                int row = m0 + wm * 64 + i * 16 + quad * 4 + r;
                int col = nb * 128 + wn * 64 + j * 16 + lane15;
                xg[(size_t)row * G4 + col] = f2bf(acc[i][j][r]);
            }
}

// ---------------------------------------------------------------------------
// Kernel 2: recurrence via MFMA. Block = 16 batches, 4 waves.
// Wave w, lane l owns unit u = w*16 + (l&15); its 4 accumulators (gates
// i,j,f,o at cols u+g*64) hold batches quad*4+reg  (C-layout rows).
// h round-trips through sH in A-operand chunk layout [kq][m][8j].
__global__ __launch_bounds__(256)
void lstm_rec(const ushort* __restrict__ xg, const ushort* __restrict__ whT,
              const float* __restrict__ bias, float* __restrict__ out, int B)
{
    __shared__ ushort sWh[8 * 256 * 8];  // 32 KB, [kq][n][8j]
    __shared__ ushort sH[8 * 16 * 8];    // 2 KB,  [kq][m][8j]

    const int t = threadIdx.x;
    const int w = t >> 6, l = t & 63;
    const int lane15 = l & 15, quad = l >> 4;
    const int u = w * 16 + lane15;
    const int b0 = blockIdx.x * 16;

    // DMA Wh: 32 KB = 32 x 1KB chunks; 8 per wave.  (R2 bug: staged only 16)
    {
        const char* g = (const char*)whT;
        char* s = (char*)sWh;
        #pragma unroll
        for (int q = 0; q < 8; ++q) {
            int off = (w * 8 + q) * 1024;
            gl_lds16(g + off + l * 16, s + off);
        }
    }
    // zero h buffer: 2048 B / 256 threads = 8 B each
    ((uint2*)sH)[t] = (uint2){0u, 0u};

    float bia[4];
    bia[0] = bias[u];
    bia[1] = bias[64 + u];
    bia[2] = bias[128 + u] + 1.0f;   // FORGET_BIAS folded
    bia[3] = bias[192 + u];

    float cst[4] = {0.f, 0.f, 0.f, 0.f};
    __syncthreads();

    for (int step = 0; step < T_STEPS; ++step) {
        // ---- init acc from xg + bias
        f32x4 acc[4];
        #pragma unroll
        for (int g = 0; g < 4; ++g) {
            #pragma unroll
            for (int r = 0; r < 4; ++r) {
                int m = quad * 4 + r;
                acc[g][r] = bf2f(xg[((size_t)(b0 + m) * T_STEPS + step) * G4 + g * 64 + u]) + bia[g];
            }
        }
        // ---- h fragments (A-layout: m=lane&15, k=quad*8+j), K=64 -> 2 chunks
        short8 aF[2];
        #pragma unroll
        for (int kh = 0; kh < 2; ++kh)
            aF[kh] = *(const short8*)&sH[((kh * 4 + quad) * 16 + lane15) * 8];
        // ---- gates += h @ Wh
        #pragma unroll
        for (int g = 0; g < 4; ++g) {
            #pragma unroll
            for (int kh = 0; kh < 2; ++kh) {
                short8 bF = *(const short8*)&sWh[((kh * 4 + quad) * 256 + g * 64 + u) * 8];
                acc[g] = __builtin_amdgcn_mfma_f32_16x16x32_bf16(aF[kh], bF, acc[g], 0, 0, 0);
            }
        }
        __syncthreads();   // everyone done reading sH of this step

        // ---- activations, state update, output, new h into sH
        #pragma unroll
        for (int r = 0; r < 4; ++r) {
            int m = quad * 4 + r;
            float ii = fsig(acc[0][r]);
            float jj = ftanh(acc[1][r]);
            float ff = fsig(acc[2][r]);
            float oo = fsig(acc[3][r]);
            float c = ff * cst[r] + ii * jj;
            cst[r] = c;
            float h = oo * ftanh(c);
            out[((size_t)(b0 + m) * T_STEPS + step) * HID + u] = h;
            sH[((u >> 3) * 16 + m) * 8 + (u & 7)] = f2bf(h);
        }
        __syncthreads();   // new h visible before next step's reads
    }
}

// ---------------------------------------------------------------------------
extern "C" void kernel_launch(void* const* d_in, const int* in_sizes, int n_in,
                              void* d_out, int out_size, void* d_ws, size_t ws_size,
                              hipStream_t stream)
{
    const float* x    = (const float*)d_in[0];
    const float* kern = (const float*)d_in[1];
    const float* bias = (const float*)d_in[2];
    float* out = (float*)d_out;

    const int B = in_sizes[0] / (T_STEPS * D_IN);   // 4096
    const int M = B * T_STEPS;                      // 36864

    // ws layout
    ushort* xg  = (ushort*)d_ws;                              // 18,874,368 B
    ushort* wxT = (ushort*)((char*)d_ws + (size_t)M * G4 * 2);          // 256 KB
    ushort* whT = (ushort*)((char*)d_ws + (size_t)M * G4 * 2 + 262144); // 32 KB

    prep_w<<<576, 256, 0, stream>>>(kern, wxT, whT);

    dim3 g1(M / 128, G4 / 128);
    xg_gemm<<<g1, 256, 0, stream>>>(x, wxT, xg, M);

    lstm_rec<<<B / 16, 256, 0, stream>>>(xg, whT, bias, out, B);
}

// Round 4
// 136.380 us; speedup vs baseline: 1.9593x; 1.1643x over previous
//
#include <hip/hip_runtime.h>
#include <math.h>

#define T_STEPS 9
#define D_IN    512
#define HID     64
#define G4      256   // 4*HID
#define BPB     16    // batches per block
#define MT      144   // rows per block = BPB * T_STEPS
#define UPAD    84    // padded u-stride in LDS xg tile (84: quad stride = 8 banks)

typedef short  short8 __attribute__((ext_vector_type(8)));
typedef float  f32x4  __attribute__((ext_vector_type(4)));
typedef unsigned int uint;
typedef unsigned short ushort;

// ---------------------------------------------------------------------------
__device__ __forceinline__ ushort f2bf(float f) {
    uint u = __float_as_uint(f);
    u = (u + 0x7FFFu + ((u >> 16) & 1u)) >> 16;   // RNE
    return (ushort)u;
}
__device__ __forceinline__ float bf2f(ushort b) {
    return __uint_as_float(((uint)b) << 16);
}
__device__ __forceinline__ float fsig(float x) {
    return 1.0f / (1.0f + __expf(-x));
}
__device__ __forceinline__ float ftanh(float x) {
    float t = __expf(-2.0f * fabsf(x));
    float r = (1.0f - t) / (1.0f + t);
    return copysignf(r, x);
}
__device__ __forceinline__ void gl_lds16(const void* g, void* l) {
    __builtin_amdgcn_global_load_lds(
        (const __attribute__((address_space(1))) unsigned int*)g,
        (__attribute__((address_space(3))) unsigned int*)l, 16, 0, 0);
}

// ---------------------------------------------------------------------------
// Prepass: weights -> bf16 staging layouts.
// WxT: [k0(16)][qk(4)][n(256)][j(8)]   k = k0*32+qk*8+j   (131072 elems, 256 KB)
// WhT: [kq(8)][n(256)][j(8)]           k = kq*8+j         ( 16384 elems,  32 KB)
__global__ __launch_bounds__(256)
void prep_w(const float* __restrict__ kern, ushort* __restrict__ wxT,
            ushort* __restrict__ whT)
{
    int i = blockIdx.x * 256 + threadIdx.x;
    if (i < 131072) {
        int j  = i & 7;
        int n  = (i >> 3) & 255;
        int qk = (i >> 11) & 3;
        int k0 = i >> 13;
        int k  = k0 * 32 + qk * 8 + j;
        wxT[i] = f2bf(kern[(size_t)k * G4 + n]);
    } else {
        int i2 = i - 131072;
        int j  = i2 & 7;
        int n  = (i2 >> 3) & 255;
        int kq = i2 >> 11;
        whT[i2] = f2bf(kern[(size_t)(D_IN + kq * 8 + j) * G4 + n]);
    }
}

// ---------------------------------------------------------------------------
// Fused kernel: block = 16 batches (contiguous 144 x-rows). Phase 1 computes
// xg_tile[144][256] via MFMA into LDS (wave w owns cols g*64 + w*16 + lane15,
// so phase-2 reads are wave-local). Phase 2 runs the 9-step recurrence.
__global__ __launch_bounds__(256, 1)
void lstm_fused(const float* __restrict__ x, const ushort* __restrict__ wxT,
                const ushort* __restrict__ whT, const float* __restrict__ bias,
                float* __restrict__ out)
{
    __shared__ ushort sXg[4 * MT * UPAD];  // 94.5 KB  [g][m][u pad 84]
    __shared__ ushort sWh[8 * 256 * 8];    // 32 KB    [kq][n][j]
    __shared__ ushort sB [4 * 256 * 8];    // 16 KB    [qk][n][j]
    __shared__ ushort sA [4 * MT * 8];     // 9 KB     [qk][m][j]
    __shared__ ushort sH [8 * 16 * 8];     // 2 KB     [kq][m][j]

    const int t = threadIdx.x;
    const int w = t >> 6, l = t & 63;
    const int lane15 = l & 15, quad = l >> 4;
    const int u = w * 16 + lane15;

    // ---- DMA Wh once (32 KB = 32 x 1KB chunks, 8 per wave); drains at the
    //      phase-1 chunk barriers long before first use.
    {
        const char* g = (const char*)whT;
        char* s = (char*)sWh;
        #pragma unroll
        for (int q = 0; q < 8; ++q) {
            int off = (w * 8 + q) * 1024;
            gl_lds16(g + off + l * 16, s + off);
        }
    }

    // =======================  Phase 1: xg GEMM  ===========================
    const float* xblk = x + (size_t)blockIdx.x * MT * D_IN;   // contiguous rows
    // A-stage mapping: half-row hr -> (m = hr>>1, kh = hr&1 covering 16 k's).
    // Thread t does hr = t; threads 0..31 also hr = t + 256.
    const int m_a  = t >> 1, kh_a = t & 1;
    const int m_b  = 128 + (t >> 1);               // only used when t < 32
    const float* pA = xblk + (size_t)m_a * D_IN + kh_a * 16;
    const float* pB = xblk + (size_t)m_b * D_IN + kh_a * 16;

    float4 rA[4], rB[4];
    #pragma unroll
    for (int q = 0; q < 4; ++q) rA[q] = ((const float4*)pA)[q];
    if (t < 32) {
        #pragma unroll
        for (int q = 0; q < 4; ++q) rB[q] = ((const float4*)pB)[q];
    }

    f32x4 acc[9][4];
    #pragma unroll
    for (int i = 0; i < 9; ++i)
        #pragma unroll
        for (int j = 0; j < 4; ++j)
            acc[i][j] = (f32x4){0.f, 0.f, 0.f, 0.f};

    for (int k0 = 0; k0 < 16; ++k0) {
        __syncthreads();   // protect sA/sB reuse from previous chunk's readers
        // ---- write sA from prefetched registers (fp32 -> bf16)
        {
            uint4 lo, hi;
            lo.x = f2bf(rA[0].x) | ((uint)f2bf(rA[0].y) << 16);
            lo.y = f2bf(rA[0].z) | ((uint)f2bf(rA[0].w) << 16);
            lo.z = f2bf(rA[1].x) | ((uint)f2bf(rA[1].y) << 16);
            lo.w = f2bf(rA[1].z) | ((uint)f2bf(rA[1].w) << 16);
            hi.x = f2bf(rA[2].x) | ((uint)f2bf(rA[2].y) << 16);
            hi.y = f2bf(rA[2].z) | ((uint)f2bf(rA[2].w) << 16);
            hi.z = f2bf(rA[3].x) | ((uint)f2bf(rA[3].y) << 16);
            hi.w = f2bf(rA[3].z) | ((uint)f2bf(rA[3].w) << 16);
            *(uint4*)&sA[((kh_a * 2 + 0) * MT + m_a) * 8] = lo;
            *(uint4*)&sA[((kh_a * 2 + 1) * MT + m_a) * 8] = hi;
            if (t < 32) {
                uint4 lo2, hi2;
                lo2.x = f2bf(rB[0].x) | ((uint)f2bf(rB[0].y) << 16);
                lo2.y = f2bf(rB[0].z) | ((uint)f2bf(rB[0].w) << 16);
                lo2.z = f2bf(rB[1].x) | ((uint)f2bf(rB[1].y) << 16);
                lo2.w = f2bf(rB[1].z) | ((uint)f2bf(rB[1].w) << 16);
                hi2.x = f2bf(rB[2].x) | ((uint)f2bf(rB[2].y) << 16);
                hi2.y = f2bf(rB[2].z) | ((uint)f2bf(rB[2].w) << 16);
                hi2.z = f2bf(rB[3].x) | ((uint)f2bf(rB[3].y) << 16);
                hi2.w = f2bf(rB[3].z) | ((uint)f2bf(rB[3].w) << 16);
                *(uint4*)&sA[((kh_a * 2 + 0) * MT + m_b) * 8] = lo2;
                *(uint4*)&sA[((kh_a * 2 + 1) * MT + m_b) * 8] = hi2;
            }
        }
        // ---- DMA sB chunk: 16 KB, 4 x 1KB per wave
        {
            const char* gb = (const char*)wxT + (size_t)k0 * 16384;
            char* lb = (char*)sB;
            #pragma unroll
            for (int q = 0; q < 4; ++q) {
                int off = w * 4096 + q * 1024;
                gl_lds16(gb + off + l * 16, lb + off);
            }
        }
        __syncthreads();   // drains DMA + sA writes

        // ---- prefetch next chunk's x into registers (overlaps MFMA below)
        if (k0 < 15) {
            const float4* nA = (const float4*)(pA + (k0 + 1) * 32);
            #pragma unroll
            for (int q = 0; q < 4; ++q) rA[q] = nA[q];
            if (t < 32) {
                const float4* nB = (const float4*)(pB + (k0 + 1) * 32);
                #pragma unroll
                for (int q = 0; q < 4; ++q) rB[q] = nB[q];
            }
        }

        // ---- fragments + MFMA: wave w's N-tiles at n = j*64 + w*16
        short8 bF[4];
        #pragma unroll
        for (int j = 0; j < 4; ++j)
            bF[j] = *(const short8*)&sB[(quad * 256 + j * 64 + w * 16 + lane15) * 8];
        #pragma unroll
        for (int i = 0; i < 9; ++i) {
            short8 aF = *(const short8*)&sA[(quad * MT + i * 16 + lane15) * 8];
            #pragma unroll
            for (int j = 0; j < 4; ++j)
                acc[i][j] = __builtin_amdgcn_mfma_f32_16x16x32_bf16(aF, bF[j], acc[i][j], 0, 0, 0);
        }
    }

    // ---- epilogue: C-layout (col = lane15 -> u, row = quad*4+r) into sXg.
    // Wave w writes exactly the (g, u = w*16+lane15) slice it reads in phase 2.
    #pragma unroll
    for (int i = 0; i < 9; ++i)
        #pragma unroll
        for (int j = 0; j < 4; ++j)
            #pragma unroll
            for (int r = 0; r < 4; ++r) {
                int m = i * 16 + quad * 4 + r;
                sXg[(j * MT + m) * UPAD + u] = f2bf(acc[i][j][r]);
            }

    // =======================  Phase 2: recurrence  ========================
    ((uint2*)sH)[t] = (uint2){0u, 0u};   // h_0 = 0

    float bia[4];
    bia[0] = bias[u];
    bia[1] = bias[64 + u];
    bia[2] = bias[128 + u] + 1.0f;       // FORGET_BIAS folded
    bia[3] = bias[192 + u];

    float cst[4] = {0.f, 0.f, 0.f, 0.f};
    const int b0 = blockIdx.x * BPB;
    __syncthreads();                     // sH zero visible to all waves

    for (int step = 0; step < T_STEPS; ++step) {
        // ---- init gates from LDS xg (wave-local) + bias
        f32x4 g4[4];
        #pragma unroll
        for (int g = 0; g < 4; ++g) {
            #pragma unroll
            for (int r = 0; r < 4; ++r) {
                int m = (quad * 4 + r) * T_STEPS + step;
                g4[g][r] = bf2f(sXg[(g * MT + m) * UPAD + u]) + bia[g];
            }
        }
        // ---- h fragments (A-layout), K=64 -> 2 chunks
        short8 aF[2];
        #pragma unroll
        for (int kh = 0; kh < 2; ++kh)
            aF[kh] = *(const short8*)&sH[((kh * 4 + quad) * 16 + lane15) * 8];
        // ---- gates += h @ Wh
        #pragma unroll
        for (int g = 0; g < 4; ++g) {
            #pragma unroll
            for (int kh = 0; kh < 2; ++kh) {
                short8 bF = *(const short8*)&sWh[((kh * 4 + quad) * 256 + g * 64 + u) * 8];
                g4[g] = __builtin_amdgcn_mfma_f32_16x16x32_bf16(aF[kh], bF, g4[g], 0, 0, 0);
            }
        }
        __syncthreads();   // all waves done reading this step's sH

        // ---- activations, state, output, next h
        #pragma unroll
        for (int r = 0; r < 4; ++r) {
            int bi = quad * 4 + r;
            float ii = fsig(g4[0][r]);
            float jj = ftanh(g4[1][r]);
            float ff = fsig(g4[2][r]);
            float oo = fsig(g4[3][r]);
            float c = ff * cst[r] + ii * jj;
            cst[r] = c;
            float h = oo * ftanh(c);
            out[((size_t)(b0 + bi) * T_STEPS + step) * HID + u] = h;
            sH[((u >> 3) * 16 + bi) * 8 + (u & 7)] = f2bf(h);
        }
        __syncthreads();   // new h visible before next step's reads
    }
}

// ---------------------------------------------------------------------------
extern "C" void kernel_launch(void* const* d_in, const int* in_sizes, int n_in,
                              void* d_out, int out_size, void* d_ws, size_t ws_size,
                              hipStream_t stream)
{
    const float* x    = (const float*)d_in[0];
    const float* kern = (const float*)d_in[1];
    const float* bias = (const float*)d_in[2];
    float* out = (float*)d_out;

    const int B = in_sizes[0] / (T_STEPS * D_IN);   // 4096

    ushort* wxT = (ushort*)d_ws;                    // 256 KB
    ushort* whT = (ushort*)((char*)d_ws + 262144);  // 32 KB

    prep_w<<<576, 256, 0, stream>>>(kern, wxT, whT);
    lstm_fused<<<B / BPB, 256, 0, stream>>>(x, wxT, whT, bias, out);
}